// Round 1
// baseline (118.022 us; speedup 1.0000x reference)
//
#include <hip/hip_runtime.h>
#include <hip/hip_bf16.h>

// FourierKANLayer: out[n,o] = bias[o] + sum_{i,b} coeffs[o,i,b] * basis[n,i,b]
// basis = [1, sin(m*pi*x) m=1..32, cos(m*pi*x) m=1..32] per (n,i).
//
// R2 design: keep R1's 32x32x16 MFMA / Chebyshev / global_load_lds staging,
// but kill the per-mode vmcnt(0) drain: 4-deep LDS ring buffer, stage 2 modes
// ahead, counted `s_waitcnt vmcnt(8)` + raw s_barrier (T3/T4 pattern) so
// prefetch loads stay in flight across barriers. Chebyshev state packed as
// float2 (sin,cos) to enable v_pk_fma_f32 / v_cvt_pk_bf16_f32.

typedef __bf16 bf16x8 __attribute__((ext_vector_type(8)));
typedef float  f32x2  __attribute__((ext_vector_type(2)));
typedef float  f32x4  __attribute__((ext_vector_type(4)));
typedef float  f32x16 __attribute__((ext_vector_type(16)));

#define PI_F 3.14159265358979323846f

// ---------------------------------------------------------------------------
// Repack coeffs [64][64][65] fp32 -> Bp bf16 in 32x32x16 B-fragment order.
// frag = (m*8 + kc)*2 + cc   (m=mode-1 in [0,32), kc in [0,8), cc in [0,2))
// lane: col o = cc*32 + (lane&31), kq = lane>>5
// t in [0,8): k_local = kc*16 + kq*8 + t; i = kc*8 + kq*4 + (t>>1)
//             b = (t&1) ? 33+m : 1+m
// Bp[frag*512 + lane*8 + t] = coeffs[o][i][b]
// bias2[o] = bias[o] + sum_i coeffs[o][i][0]  (block 0, threads 0..63).
// ---------------------------------------------------------------------------
__global__ __launch_bounds__(256) void fkan_repack(
    const float* __restrict__ coeffs, const float* __restrict__ bias,
    __bf16* __restrict__ Bp, float* __restrict__ bias2) {
  int gid  = blockIdx.x * 256 + threadIdx.x;   // 0 .. 32767
  int lane = gid & 63;
  int frag = gid >> 6;                          // 0..511
  int m  = frag >> 4;
  int kc = (frag >> 1) & 7;
  int cc = frag & 1;
  int o  = cc * 32 + (lane & 31);
  int kq = lane >> 5;

  bf16x8 v;
  #pragma unroll
  for (int t = 0; t < 8; ++t) {
    int i = kc * 8 + kq * 4 + (t >> 1);
    int b = (t & 1) ? (33 + m) : (1 + m);
    v[t] = (__bf16)coeffs[(o * 64 + i) * 65 + b];
  }
  *(bf16x8*)(Bp + (size_t)frag * 512 + lane * 8) = v;

  if (blockIdx.x == 0 && threadIdx.x < 64) {
    int oo = threadIdx.x;
    float s = bias[oo];
    #pragma unroll 4
    for (int ii = 0; ii < 64; ++ii) s += coeffs[(oo * 64 + ii) * 65 + 0];
    bias2[oo] = s;
  }
}

// ---------------------------------------------------------------------------
// Staging: each wave DMAs its 4 KB quarter of mode m's 16 KB B-tile into the
// ring buffer slot. 4 x global_load_lds width=16; LDS dest is wave-uniform
// base + lane*16 (HW requirement).
// ---------------------------------------------------------------------------
__device__ __forceinline__ void stage_slice(const __bf16* __restrict__ Bp,
                                            __bf16* dst, int m, int wave,
                                            int lane) {
  const char* g = (const char*)Bp + (size_t)m * 16384 + wave * 4096 + lane * 16;
  char* l = (char*)dst + wave * 4096;
  #pragma unroll
  for (int r = 0; r < 4; ++r) {
    __builtin_amdgcn_global_load_lds(
        (const __attribute__((address_space(1))) void*)(g + r * 1024),
        (__attribute__((address_space(3))) void*)(l + r * 1024), 16, 0, 0);
  }
}

// Counted vmem wait + raw barrier: the whole point is NOT draining vmcnt to 0,
// so the 2-mode-deep global_load_lds pipeline survives the barrier (T3/T4).
#define ASM_VMCNT(N) asm volatile("s_waitcnt vmcnt(" #N ")" ::: "memory")

__device__ __forceinline__ void block_barrier() {
  asm volatile("" ::: "memory");   // compiler fence: no LDS-op motion across
  __builtin_amdgcn_s_barrier();
  asm volatile("" ::: "memory");
}

// ---------------------------------------------------------------------------
// One mode: 8 A-frags built from packed (sin,cos) state, 16 B-frags
// (ds_read_b128) from the ring slot, 16 MFMA 32x32x16, then Chebyshev
// advance writes the next mode's values into `nxt` (role swap per mode).
// All indices compile-time after unroll -> stays in registers.
// ---------------------------------------------------------------------------
__device__ __forceinline__ void compute_mode(const __bf16* bsrc, int lane,
                                             const f32x2* cur, f32x2* nxt,
                                             const float* T, f32x16* acc) {
  #pragma unroll
  for (int kc = 0; kc < 8; ++kc) {
    bf16x8 af;
    #pragma unroll
    for (int e = 0; e < 4; ++e) {
      af[2 * e]     = (__bf16)cur[kc * 4 + e][0];   // sin
      af[2 * e + 1] = (__bf16)cur[kc * 4 + e][1];   // cos
    }
    #pragma unroll
    for (int c2 = 0; c2 < 2; ++c2) {
      bf16x8 bf = *(const bf16x8*)(bsrc + (kc * 2 + c2) * 512 + lane * 8);
      acc[c2] = __builtin_amdgcn_mfma_f32_32x32x16_bf16(af, bf, acc[c2],
                                                        0, 0, 0);
    }
  }
  // Chebyshev advance: nxt <- T*cur - nxt   (packed, hoping for v_pk_fma_f32)
  #pragma unroll
  for (int p = 0; p < 32; ++p) {
    f32x2 n;
    n[0] = fmaf(T[p], cur[p][0], -nxt[p][0]);
    n[1] = fmaf(T[p], cur[p][1], -nxt[p][1]);
    nxt[p] = n;
  }
}

// ---------------------------------------------------------------------------
// Main kernel: 256 threads = 4 waves; block = 128 rows x 64 cols; grid = 512.
// Wave w: rows [blk*128 + w*32, +32). Lane: row = lane&31, kq = lane>>5.
// Ring: Bs[4][16KB]; at mode m stage m+2, wait vmcnt(8) (= mode m landed,
// m+1/m+2 still in flight), raw barrier, compute.
// Race check: slot (m+2)&3 was last read at mode m-2, and the mode m-1
// barrier separates that read from this write.
// ---------------------------------------------------------------------------
__global__ __launch_bounds__(256, 2) void fkan_main(
    const float* __restrict__ x, const __bf16* __restrict__ Bp,
    const float* __restrict__ bias2, float* __restrict__ out) {
  __shared__ __bf16 Bs[4][8192];   // 4 x 16 KB ring buffer (64 KB)

  int tid  = threadIdx.x;
  int wave = tid >> 6;
  int lane = tid & 63;
  int kq   = lane >> 5;
  int cl   = lane & 31;
  int row  = blockIdx.x * 128 + wave * 32 + cl;

  // --- init: sincos(pi*x) for the lane's 32 (row,i) instances -------------
  float T[32];
  f32x2 cur[32], prv[32];          // cur = mode m values, prv = mode m-1
  const float* xrow = x + (size_t)row * 64 + kq * 4;
  #pragma unroll
  for (int kc = 0; kc < 8; ++kc) {
    f32x4 v = *(const f32x4*)(xrow + kc * 8);
    #pragma unroll
    for (int e = 0; e < 4; ++e) {
      int p = kc * 4 + e;
      float ss, cs;
      __sincosf(PI_F * v[e], &ss, &cs);
      T[p] = 2.0f * cs;                    // Chebyshev multiplier
      cur[p][0] = ss;  cur[p][1] = cs;     // mode 1
      prv[p][0] = 0.f; prv[p][1] = 1.f;    // mode 0
    }
  }

  f32x16 acc[2];
  #pragma unroll
  for (int c2 = 0; c2 < 2; ++c2)
    #pragma unroll
    for (int r = 0; r < 16; ++r) acc[c2][r] = 0.f;

  // --- prologue: 2-deep prefetch ------------------------------------------
  stage_slice(Bp, &Bs[0][0], 0, wave, lane);
  stage_slice(Bp, &Bs[1][0], 1, wave, lane);

  // --- main loop: modes 0..27, counted-vmcnt pipeline ---------------------
  #pragma unroll 1
  for (int mm = 0; mm < 28; mm += 2) {
    stage_slice(Bp, &Bs[(mm + 2) & 3][0], mm + 2, wave, lane);
    ASM_VMCNT(8);                  // mode mm's stage complete (8 newer in flight)
    block_barrier();
    compute_mode(&Bs[mm & 3][0], lane, cur, prv, T, acc);      // mode mm

    stage_slice(Bp, &Bs[(mm + 3) & 3][0], mm + 3, wave, lane);
    ASM_VMCNT(8);                  // mode mm+1's stage complete
    block_barrier();
    compute_mode(&Bs[(mm + 1) & 3][0], lane, prv, cur, T, acc); // mode mm+1
  }

  // --- peeled tail: modes 28..31 (vmcnt immediates shrink) ----------------
  stage_slice(Bp, &Bs[2][0], 30, wave, lane);
  ASM_VMCNT(8);  block_barrier();
  compute_mode(&Bs[0][0], lane, cur, prv, T, acc);   // mode 28

  stage_slice(Bp, &Bs[3][0], 31, wave, lane);
  ASM_VMCNT(8);  block_barrier();
  compute_mode(&Bs[1][0], lane, prv, cur, T, acc);   // mode 29

  ASM_VMCNT(4);  block_barrier();
  compute_mode(&Bs[2][0], lane, cur, prv, T, acc);   // mode 30

  ASM_VMCNT(0);  block_barrier();
  compute_mode(&Bs[3][0], lane, prv, cur, T, acc);   // mode 31

  // --- epilogue: C/D layout col=lane&31, row=(r&3)+8*(r>>2)+4*(lane>>5) ---
  float* orow = out + (size_t)(blockIdx.x * 128 + wave * 32) * 64;
  #pragma unroll
  for (int c2 = 0; c2 < 2; ++c2) {
    float b2 = bias2[c2 * 32 + cl];
    #pragma unroll
    for (int r = 0; r < 16; ++r) {
      int ro = (r & 3) + 8 * (r >> 2) + 4 * kq;
      orow[(size_t)ro * 64 + c2 * 32 + cl] = acc[c2][r] + b2;
    }
  }
}

extern "C" void kernel_launch(void* const* d_in, const int* in_sizes, int n_in,
                              void* d_out, int out_size, void* d_ws, size_t ws_size,
                              hipStream_t stream) {
  const float* x      = (const float*)d_in[0];   // [65536, 64]
  const float* coeffs = (const float*)d_in[1];   // [64, 64, 65]
  const float* bias   = (const float*)d_in[2];   // [64]
  float* out = (float*)d_out;

  __bf16* Bp   = (__bf16*)d_ws;                  // 512 KB
  float* bias2 = (float*)((char*)d_ws + 512 * 1024);

  int n_rows = in_sizes[0] / 64;                 // 65536

  fkan_repack<<<128, 256, 0, stream>>>(coeffs, bias, Bp, bias2);
  fkan_main<<<n_rows / 128, 256, 0, stream>>>(x, Bp, bias2, out);
}